// Round 1
// baseline (12554.225 us; speedup 1.0000x reference)
//
#include <hip/hip_runtime.h>

#define NPOS 65536   // 64 batches * 32 * 32 positions
#define NE   121     // 11*11 tensor entries

// ------------------------------------------------------------------
// f0: 8-channel 3x3 tensorized conv, 16x16 -> 11x11, writes raw y.
// Grid: 2048 blocks (XCD-swizzled) = (b,h). Block: 256 thr = (c, w).
// ------------------------------------------------------------------
__global__ __launch_bounds__(256, 2)
void f0_kernel(const float* __restrict__ x, const float* __restrict__ U,
               const float* __restrict__ V, float* __restrict__ y) {
  __shared__ float smem[2816];                // U(1408) + V(1408); reused for reduce
  int bid = blockIdx.x;
  int wg  = (bid & 7) * 256 + (bid >> 3);     // XCD-contiguous swizzle (2048 % 8 == 0)
  int b = wg >> 5, h = wg & 31;
  int t = threadIdx.x;
  int c = t >> 5, w = t & 31;

  float Y[11][11];
#pragma unroll
  for (int p = 0; p < 11; ++p)
#pragma unroll
    for (int q = 0; q < 11; ++q) Y[p][q] = 0.f;

  for (int ij = 0; ij < 9; ++ij) {
    __syncthreads();
    for (int idx = t; idx < 1408; idx += 256) {
      int cc = idx / 176, pm = idx % 176;     // U[c][ij][p][m] : (c*9+ij)*176 + p*16+m
      smem[idx]        = U[(cc * 9 + ij) * 176 + pm];
      smem[1408 + idx] = V[(cc * 9 + ij) * 176 + pm];
    }
    __syncthreads();
    int i = ij / 3, j = ij - 3 * (ij / 3);
    int hi = h + i - 1, wj = w + j - 1;
    if ((unsigned)hi < 32u && (unsigned)wj < 32u) {
      // x element (m,n) of this (b,c,pos): base + (m*16+n)*1024
      const float* xb = x + ((size_t)(b * 8 + c) << 18) + (hi << 5) + wj;
      const float* uB = &smem[c * 176];
      const float* vB = &smem[1408 + c * 176];
      for (int nc = 0; nc < 4; ++nc) {        // n in chunks of 4 (register economy)
        float A[11][4];
#pragma unroll
        for (int p = 0; p < 11; ++p)
#pragma unroll
          for (int k = 0; k < 4; ++k) A[p][k] = 0.f;
        for (int m = 0; m < 16; ++m) {
          float Xr[4];
#pragma unroll
          for (int k = 0; k < 4; ++k)
            Xr[k] = xb[(m * 16 + nc * 4 + k) << 10];
#pragma unroll
          for (int p = 0; p < 11; ++p) {
            float u = uB[p * 16 + m];
#pragma unroll
            for (int k = 0; k < 4; ++k) A[p][k] += u * Xr[k];
          }
        }
        for (int k = 0; k < 4; ++k) {
          float vc[11];
#pragma unroll
          for (int q = 0; q < 11; ++q) vc[q] = vB[q * 16 + nc * 4 + k];
#pragma unroll
          for (int p = 0; p < 11; ++p)
#pragma unroll
            for (int q = 0; q < 11; ++q) Y[p][q] += A[p][k] * vc[q];
        }
      }
    }
  }

  // reduce over c (8 threads per (w,p,q)) through LDS, row p at a time
  int posb = ((b << 5) + h) << 5;
#pragma unroll
  for (int p = 0; p < 11; ++p) {
    __syncthreads();
#pragma unroll
    for (int q = 0; q < 11; ++q) smem[(c * 32 + w) * 11 + q] = Y[p][q];
    __syncthreads();
    for (int idx = t; idx < 352; idx += 256) {
      int qq = idx >> 5, w2 = idx & 31;
      float s = 0.f;
#pragma unroll
      for (int cc = 0; cc < 8; ++cc) s += smem[(cc * 32 + w2) * 11 + qq];
      y[(size_t)(p * 11 + qq) * NPOS + posb + w2] = s;
    }
  }
}

// ------------------------------------------------------------------
// TBN stats: partial sums (484 blocks = 121 entries x 4 quarters),
// then finalize scale/shift. No atomics -> bit-deterministic.
// ------------------------------------------------------------------
__global__ __launch_bounds__(256)
void stats_partial(const float* __restrict__ raw, float* __restrict__ part) {
  int blk = blockIdx.x;
  int e = blk >> 2, qt = blk & 3;
  const float4* p = (const float4*)(raw + (size_t)e * NPOS) + qt * 4096;
  int t = threadIdx.x;
  float s = 0.f, s2 = 0.f;
  for (int i = t; i < 4096; i += 256) {
    float4 v = p[i];
    s  += v.x + v.y + v.z + v.w;
    s2 += v.x * v.x + v.y * v.y + v.z * v.z + v.w * v.w;
  }
#pragma unroll
  for (int o = 32; o > 0; o >>= 1) {
    s  += __shfl_down(s, o);
    s2 += __shfl_down(s2, o);
  }
  __shared__ float ls[8];
  int wid = t >> 6;
  if ((t & 63) == 0) { ls[wid] = s; ls[4 + wid] = s2; }
  __syncthreads();
  if (t == 0) {
    part[blk]       = ls[0] + ls[1] + ls[2] + ls[3];
    part[484 + blk] = ls[4] + ls[5] + ls[6] + ls[7];
  }
}

__global__ void stats_final(const float* __restrict__ part, const float* __restrict__ g,
                            const float* __restrict__ bb, float* __restrict__ sc,
                            float* __restrict__ sh) {
  int e = threadIdx.x;
  if (e < 121) {
    float s  = part[e * 4] + part[e * 4 + 1] + part[e * 4 + 2] + part[e * 4 + 3];
    float s2 = part[484 + e * 4] + part[484 + e * 4 + 1] +
               part[484 + e * 4 + 2] + part[484 + e * 4 + 3];
    float mu  = s  * (1.f / 65536.f);
    float var = s2 * (1.f / 65536.f) - mu * mu;
    float sca = g[e] * rsqrtf(var + 1e-5f);
    sc[e] = sca;
    sh[e] = bb[e] - mu * sca;
  }
}

// ------------------------------------------------------------------
// tconv1x1: out_raw = U * hin * V^T per position.
// hin = affine(A) [+ affine(B)] [then PReLU(alpha)], applied on load.
// ------------------------------------------------------------------
template<bool HASB, bool PRELU>
__global__ __launch_bounds__(256, 2)
void conv1x1_kernel(const float* __restrict__ rA, const float* __restrict__ scA,
                    const float* __restrict__ shA,
                    const float* __restrict__ rB, const float* __restrict__ scB,
                    const float* __restrict__ shB,
                    const float* __restrict__ alpha_ptr, int alpha_idx,
                    const float* __restrict__ U, const float* __restrict__ V,
                    float* __restrict__ out) {
  __shared__ float su[121], sv[121], sa[242], sb[242];
  int t = threadIdx.x;
  if (t < 121) {
    su[t] = U[t]; sv[t] = V[t];
    sa[t] = scA[t]; sb[t] = shA[t];
    if (HASB) { sa[121 + t] = scB[t]; sb[121 + t] = shB[t]; }
  }
  __syncthreads();
  float alpha = 0.f;
  if (PRELU) alpha = alpha_ptr[alpha_idx];
  size_t pos = (size_t)blockIdx.x * 256 + t;

  float T[11][11];
#pragma unroll
  for (int p = 0; p < 11; ++p)
#pragma unroll
    for (int n = 0; n < 11; ++n) T[p][n] = 0.f;

#pragma unroll
  for (int m = 0; m < 11; ++m) {
    float Xr[11];
#pragma unroll
    for (int n = 0; n < 11; ++n) {
      int e = m * 11 + n;
      float v = sa[e] * rA[(size_t)e * NPOS + pos] + sb[e];
      if (HASB) v += sa[121 + e] * rB[(size_t)e * NPOS + pos] + sb[121 + e];
      if (PRELU) v = v >= 0.f ? v : alpha * v;
      Xr[n] = v;
    }
#pragma unroll
    for (int p = 0; p < 11; ++p) {
      float u = su[p * 11 + m];
#pragma unroll
      for (int n = 0; n < 11; ++n) T[p][n] += u * Xr[n];
    }
  }
  // Y[:,q] streamed: keeps live registers at T[121]+11
#pragma unroll
  for (int q = 0; q < 11; ++q) {
    float Yc[11];
#pragma unroll
    for (int p = 0; p < 11; ++p) Yc[p] = 0.f;
#pragma unroll
    for (int n = 0; n < 11; ++n) {
      float v = sv[q * 11 + n];
#pragma unroll
      for (int p = 0; p < 11; ++p) Yc[p] += T[p][n] * v;
    }
#pragma unroll
    for (int p = 0; p < 11; ++p) out[(size_t)(p * 11 + q) * NPOS + pos] = Yc[p];
  }
}

// ------------------------------------------------------------------
// tconv3x3 helper: one n-chunk [N0, N0+NW) of T = U*X, then Y += T*V^T
// ------------------------------------------------------------------
template<int N0, int NW>
__device__ __forceinline__ void c3_chunk(const float* __restrict__ rA,
    const float* __restrict__ sa, const float* __restrict__ sh,
    const float* __restrict__ su, const float* __restrict__ sv,
    float alpha, bool valid, int npos, float (&Y)[11][11]) {
  float T[11][NW];
#pragma unroll
  for (int p = 0; p < 11; ++p)
#pragma unroll
    for (int k = 0; k < NW; ++k) T[p][k] = 0.f;
#pragma unroll
  for (int m = 0; m < 11; ++m) {
    float Xr[NW];
#pragma unroll
    for (int k = 0; k < NW; ++k) {
      float v = 0.f;
      if (valid) {  // zero padding: padded entries are 0, NOT affine(0)
        int e = m * 11 + N0 + k;
        v = sa[e] * rA[(size_t)e * NPOS + npos] + sh[e];
        v = v >= 0.f ? v : alpha * v;
      }
      Xr[k] = v;
    }
#pragma unroll
    for (int p = 0; p < 11; ++p) {
      float u = su[p * 11 + m];
#pragma unroll
      for (int k = 0; k < NW; ++k) T[p][k] += u * Xr[k];
    }
  }
#pragma unroll
  for (int k = 0; k < NW; ++k) {
#pragma unroll
    for (int q = 0; q < 11; ++q) {
      float v = sv[q * 11 + N0 + k];
#pragma unroll
      for (int p = 0; p < 11; ++p) Y[p][q] += T[p][k] * v;
    }
  }
}

__global__ __launch_bounds__(256, 2)
void conv3x3_kernel(const float* __restrict__ rA, const float* __restrict__ scA,
                    const float* __restrict__ shA,
                    const float* __restrict__ alpha_ptr, int alpha_idx,
                    const float* __restrict__ U, const float* __restrict__ V,
                    float* __restrict__ out) {
  __shared__ float su[1089], sv[1089], sa[121], sh[121];
  int t = threadIdx.x;
  for (int idx = t; idx < 1089; idx += 256) { su[idx] = U[idx]; sv[idx] = V[idx]; }
  if (t < 121) { sa[t] = scA[t]; sh[t] = shA[t]; }
  __syncthreads();
  float alpha = alpha_ptr[alpha_idx];
  int pos = blockIdx.x * 256 + t;
  int b = pos >> 10, h = (pos >> 5) & 31, w = pos & 31;

  float Y[11][11];
#pragma unroll
  for (int p = 0; p < 11; ++p)
#pragma unroll
    for (int q = 0; q < 11; ++q) Y[p][q] = 0.f;

  for (int ij = 0; ij < 9; ++ij) {
    int i = ij / 3, j = ij - 3 * (ij / 3);
    int hi = h + i - 1, wj = w + j - 1;
    bool valid = (unsigned)hi < 32u && (unsigned)wj < 32u;
    int npos = ((b << 5) + hi) * 32 + wj;
    c3_chunk<0, 6>(rA, sa, sh, &su[ij * 121], &sv[ij * 121], alpha, valid, npos, Y);
    c3_chunk<6, 5>(rA, sa, sh, &su[ij * 121], &sv[ij * 121], alpha, valid, npos, Y);
  }
#pragma unroll
  for (int p = 0; p < 11; ++p)
#pragma unroll
    for (int q = 0; q < 11; ++q)
      out[(size_t)(p * 11 + q) * NPOS + pos] = Y[p][q];
}

// ------------------------------------------------------------------
// fcn head: out[b,o,h,w] = sum_e h[e] * W[o,e];  h = affine(A)+affine(B)
// ------------------------------------------------------------------
__global__ __launch_bounds__(256)
void head_kernel(const float* __restrict__ rA, const float* __restrict__ scA,
                 const float* __restrict__ shA,
                 const float* __restrict__ rB, const float* __restrict__ scB,
                 const float* __restrict__ shB,
                 const float* __restrict__ W, float* __restrict__ out) {
  __shared__ float sw[21 * 121], sa[242], sh[242];
  int t = threadIdx.x;
  for (int idx = t; idx < 2541; idx += 256) sw[idx] = W[idx];
  if (t < 121) {
    sa[t] = scA[t]; sh[t] = shA[t];
    sa[121 + t] = scB[t]; sh[121 + t] = shB[t];
  }
  __syncthreads();
  size_t pos = (size_t)blockIdx.x * 256 + t;
  int b = (int)(pos >> 10), hw = (int)(pos & 1023);
  float X[121];
#pragma unroll
  for (int e = 0; e < 121; ++e) {
    X[e] = sa[e] * rA[(size_t)e * NPOS + pos] + sh[e] +
           sa[121 + e] * rB[(size_t)e * NPOS + pos] + sh[121 + e];
  }
  for (int o = 0; o < 21; ++o) {
    float acc = 0.f;
#pragma unroll
    for (int e = 0; e < 121; ++e) acc += X[e] * sw[o * 121 + e];
    out[(size_t)(b * 21 + o) * 1024 + hw] = acc;
  }
}

// ------------------------------------------------------------------
extern "C" void kernel_launch(void* const* d_in, const int* in_sizes, int n_in,
                              void* d_out, int out_size, void* d_ws, size_t ws_size,
                              hipStream_t stream) {
  (void)in_sizes; (void)n_in; (void)out_size; (void)ws_size;
  const float* x     = (const float*)d_in[0];
  const float* f0_U  = (const float*)d_in[1];
  const float* f0_V  = (const float*)d_in[2];
  const float* f0_g  = (const float*)d_in[3];
  const float* f0_b  = (const float*)d_in[4];
  const float* f0_a  = (const float*)d_in[5];
  const float* s_U   = (const float*)d_in[6];
  const float* s_V   = (const float*)d_in[7];
  const float* s_g   = (const float*)d_in[8];
  const float* s_b   = (const float*)d_in[9];
  const float* bU1   = (const float*)d_in[10];
  const float* bV1   = (const float*)d_in[11];
  const float* bg1   = (const float*)d_in[12];
  const float* bb1   = (const float*)d_in[13];
  const float* ba1   = (const float*)d_in[14];
  const float* bU2   = (const float*)d_in[15];
  const float* bV2   = (const float*)d_in[16];
  const float* bg2   = (const float*)d_in[17];
  const float* bb2   = (const float*)d_in[18];
  const float* ba2   = (const float*)d_in[19];
  const float* bU3   = (const float*)d_in[20];
  const float* bV3   = (const float*)d_in[21];
  const float* bg3   = (const float*)d_in[22];
  const float* bb3   = (const float*)d_in[23];
  const float* headW = (const float*)d_in[24];

  float* ws = (float*)d_ws;
  const size_t BUF = (size_t)NE * NPOS;           // 7,929,856 floats per buffer
  float* B[4] = { ws, ws + BUF, ws + 2 * BUF, ws + 3 * BUF };
  float* st   = ws + 4 * BUF;                     // 17 ops * (scale121 + shift121)
  float* part = st + 17 * 242;                    // 968 floats of partial sums

  auto SCp = [&](int op) { return st + op * 242; };
  auto SHp = [&](int op) { return st + op * 242 + 121; };
  auto run_stats = [&](const float* raw, const float* g, const float* bb, int op) {
    stats_partial<<<484, 256, 0, stream>>>(raw, part);
    stats_final<<<1, 128, 0, stream>>>(part, g, bb, SCp(op), SHp(op));
  };

  // ---- f0 ----
  f0_kernel<<<2048, 256, 0, stream>>>(x, f0_U, f0_V, B[0]);
  run_stats(B[0], f0_g, f0_b, 0);

  // buffer rotation: for each block k -> {idn, z1, z2, z3} buffer index
  const int bufs[4][4] = { {1,2,3,0}, {2,3,0,1}, {3,0,1,2}, {0,1,2,3} };

  const float* hA   = B[0];  const float* hAsc = SCp(0); const float* hAsh = SHp(0);
  const float* hB   = nullptr; const float* hBsc = nullptr; const float* hBsh = nullptr;

  for (int k = 0; k < 4; ++k) {
    float* idn = B[bufs[k][0]];
    float* z1  = B[bufs[k][1]];
    float* z2  = B[bufs[k][2]];
    float* z3  = B[bufs[k][3]];
    int op_idn = 1 + k * 4, op_z1 = 2 + k * 4, op_z2 = 3 + k * 4, op_z3 = 4 + k * 4;

    if (k == 0) {  // h0 = prelu(tbn(y), f0_a): single source + prelu
      conv1x1_kernel<false, true><<<256, 256, 0, stream>>>(
          hA, hAsc, hAsh, nullptr, nullptr, nullptr, f0_a, 0,
          s_U + k * 121, s_V + k * 121, idn);
      conv1x1_kernel<false, true><<<256, 256, 0, stream>>>(
          hA, hAsc, hAsh, nullptr, nullptr, nullptr, f0_a, 0,
          bU1 + k * 121, bV1 + k * 121, z1);
    } else {       // h = tbn(z3_prev) + tbn(idn_prev): two sources, no prelu
      conv1x1_kernel<true, false><<<256, 256, 0, stream>>>(
          hA, hAsc, hAsh, hB, hBsc, hBsh, nullptr, 0,
          s_U + k * 121, s_V + k * 121, idn);
      conv1x1_kernel<true, false><<<256, 256, 0, stream>>>(
          hA, hAsc, hAsh, hB, hBsc, hBsh, nullptr, 0,
          bU1 + k * 121, bV1 + k * 121, z1);
    }
    run_stats(idn, s_g + k * 121, s_b + k * 121, op_idn);
    run_stats(z1,  bg1 + k * 121, bb1 + k * 121, op_z1);

    conv3x3_kernel<<<256, 256, 0, stream>>>(
        z1, SCp(op_z1), SHp(op_z1), ba1, k,
        bU2 + k * 1089, bV2 + k * 1089, z2);
    run_stats(z2, bg2 + k * 121, bb2 + k * 121, op_z2);

    conv1x1_kernel<false, true><<<256, 256, 0, stream>>>(
        z2, SCp(op_z2), SHp(op_z2), nullptr, nullptr, nullptr, ba2, k,
        bU3 + k * 121, bV3 + k * 121, z3);
    run_stats(z3, bg3 + k * 121, bb3 + k * 121, op_z3);

    hA = z3;  hAsc = SCp(op_z3);  hAsh = SHp(op_z3);
    hB = idn; hBsc = SCp(op_idn); hBsh = SHp(op_idn);
  }

  head_kernel<<<256, 256, 0, stream>>>(hA, hAsc, hAsh, hB, hBsc, hBsh,
                                       headW, (float*)d_out);
}